// Round 11
// baseline (684.222 us; speedup 1.0000x reference)
//
#include <hip/hip_runtime.h>
#include <cstddef>

#define NNODE 10000
#define IND 512
#define HD 256
#define PAD_M 10112    // 79 * 128
#define NTILE 79
#define NTRI (NTILE * (NTILE + 1) / 2)   // 3160 lower-triangle blocks
#define NST ((NTILE + 7) / 8)            // 10 row-supertiles

typedef __attribute__((ext_vector_type(8))) short short8;
typedef __attribute__((ext_vector_type(4))) float floatx4;
typedef __attribute__((ext_vector_type(4))) unsigned short ushortx4;

#define GLOAD_LDS16(gp, lp) __builtin_amdgcn_global_load_lds( \
    (const __attribute__((address_space(1))) unsigned int*)(gp), \
    (__attribute__((address_space(3))) unsigned int*)(lp), 16, 0, 0)

// barrier that waits only on LDS ops (lgkmcnt), NOT on outstanding NT stores
#define LIGHT_BARRIER() do { \
    asm volatile("s_waitcnt lgkmcnt(0)" ::: "memory"); \
    __builtin_amdgcn_s_barrier(); \
} while (0)

// ---------------------------------------------------------------------------
// 1. count degrees
// ---------------------------------------------------------------------------
__global__ void count_kernel(const int* __restrict__ src, const int* __restrict__ dst,
                             int E, int* __restrict__ cnt_src, int* __restrict__ cnt_dst) {
    int e = blockIdx.x * blockDim.x + threadIdx.x;
    if (e < E) {
        atomicAdd(&cnt_src[src[e]], 1);
        atomicAdd(&cnt_dst[dst[e]], 1);
    }
}

// ---------------------------------------------------------------------------
// 2. dinv, dinv^2, sqrt(deg) + exclusive scan of cnt_dst -> row_ptr
// ---------------------------------------------------------------------------
__global__ __launch_bounds__(1024) void scan_kernel(const int* __restrict__ cnt_src,
                                                    const int* __restrict__ cnt_dst,
                                                    float* __restrict__ dinv,
                                                    float* __restrict__ dinv2,
                                                    float* __restrict__ dsqrt,
                                                    int* __restrict__ row_ptr) {
    int t = threadIdx.x;
    for (int i = t; i < NNODE; i += 1024) {
        float d = fmaxf((float)cnt_src[i], 1.0f);
        float di = rsqrtf(d);
        dinv[i] = di;
        dinv2[i] = di * di;
        dsqrt[i] = sqrtf(d);
    }

    __shared__ int sums[1024];
    const int CH = (NNODE + 1023) / 1024;  // 10
    int base = t * CH;
    int s = 0;
    for (int i = 0; i < CH; ++i) {
        int idx = base + i;
        if (idx < NNODE) s += cnt_dst[idx];
    }
    sums[t] = s;
    __syncthreads();
    for (int off = 1; off < 1024; off <<= 1) {
        int v = (t >= off) ? sums[t - off] : 0;
        __syncthreads();
        sums[t] += v;
        __syncthreads();
    }
    int run = (t == 0) ? 0 : sums[t - 1];
    for (int i = 0; i < CH; ++i) {
        int idx = base + i;
        if (idx < NNODE) { row_ptr[idx] = run; run += cnt_dst[idx]; }
    }
    if (t == 1023) row_ptr[NNODE] = sums[1023];
}

// ---------------------------------------------------------------------------
// 3. fill CSR (by dst)
// ---------------------------------------------------------------------------
__global__ void fill_kernel(const int* __restrict__ src, const int* __restrict__ dst,
                            int E, const int* __restrict__ row_ptr,
                            int* __restrict__ cursor, int* __restrict__ col) {
    int e = blockIdx.x * blockDim.x + threadIdx.x;
    if (e < E) {
        int v = dst[e];
        int pos = row_ptr[v] + atomicAdd(&cursor[v], 1);
        col[pos] = src[e];
    }
}

// ---------------------------------------------------------------------------
// 3b. supertile-ordered (bi,bj) table for gemm2 (8x8-block supertiles)
// ---------------------------------------------------------------------------
__global__ void order_kernel(int* __restrict__ tab) {
    int s = threadIdx.x;                 // supertile id, 0..54
    if (s >= NST * (NST + 1) / 2) return;
    int I = 0;
    while ((I + 1) * (I + 2) / 2 <= s) ++I;
    int J = s - I * (I + 1) / 2;
    auto cnt = [](int Ii, int Jj) {
        int r0 = Ii * 8, r1 = min(r0 + 8, NTILE);
        int c = 0;
        for (int bi = r0; bi < r1; ++bi) {
            int c0 = Jj * 8, c1 = min(min(c0 + 8, NTILE), bi + 1);
            c += max(0, c1 - c0);
        }
        return c;
    };
    int off = 0;
    for (int sp = 0; sp < s; ++sp) {
        int Ip = 0;
        while ((Ip + 1) * (Ip + 2) / 2 <= sp) ++Ip;
        int Jp = sp - Ip * (Ip + 1) / 2;
        off += cnt(Ip, Jp);
    }
    int r0 = I * 8, r1 = min(r0 + 8, NTILE);
    for (int bi = r0; bi < r1; ++bi) {
        int c0 = J * 8, c1 = min(min(c0 + 8, NTILE), bi + 1);
        for (int bj = c0; bj < c1; ++bj)
            tab[off++] = (bi << 16) | bj;
    }
}

// ---------------------------------------------------------------------------
// 4. combine weights w_k
// ---------------------------------------------------------------------------
__global__ void w_kernel(const float* __restrict__ lam, float* __restrict__ w) {
    if (threadIdx.x == 0 && blockIdx.x == 0) {
        float c[5];
        float s0 = 1.0f / (1.0f + expf(-lam[0]));
        c[0] = s0;
        c[1] = s0;  // reference reuses lam[0] for all_h[1]
        c[2] = 1.0f / (1.0f + expf(-lam[1]));
        c[3] = 1.0f / (1.0f + expf(-lam[2]));
        c[4] = 1.0f / (1.0f + expf(-lam[3]));
        const float TH[5][5] = {
            {5.0f, -10.0f,  7.5f, -2.5f, 0.3125f},
            {0.0f,  10.0f, -15.0f, 7.5f, -1.25f },
            {0.0f,   0.0f,  7.5f, -7.5f, 1.875f },
            {0.0f,   0.0f,  0.0f,  2.5f, -1.25f },
            {0.0f,   0.0f,  0.0f,  0.0f, 0.3125f}};
        for (int k = 0; k < 5; ++k) {
            float acc = 0.0f;
            for (int i = 0; i < 5; ++i) acc += c[i] * TH[i][k];
            w[k] = acc;
        }
    }
}

// ---------------------------------------------------------------------------
// 4c. split + transpose W -> WT [HD][IND] bf16 hi/lo
// ---------------------------------------------------------------------------
__global__ void split_wt_kernel(const float* __restrict__ W,
                                unsigned short* __restrict__ WThi,
                                unsigned short* __restrict__ WTlo) {
    int tid = blockIdx.x * blockDim.x + threadIdx.x;  // 0 .. IND*HD-1
    if (tid >= IND * HD) return;
    int n = tid & (HD - 1);
    int k = tid >> 8;
    float r = W[(size_t)k * HD + n];
    unsigned u = __float_as_uint(r);
    float hif = __uint_as_float(u & 0xFFFF0000u);
    float lof = r - hif;
    WThi[(size_t)n * IND + k] = (unsigned short)(u >> 16);
    WTlo[(size_t)n * IND + k] = (unsigned short)(__float_as_uint(lof) >> 16);
}

// ---------------------------------------------------------------------------
// 5. GEMM1 (MFMA, fused in-register hi/lo split of f32 A):
//    h = leaky_relu(in_feat @ W + b); y0 = dinv*h; zy = w0*y0.
// ---------------------------------------------------------------------------
__global__ __launch_bounds__(256) void gemm1_mfma(
    const float* __restrict__ A,
    const unsigned short* __restrict__ WThi, const unsigned short* __restrict__ WTlo,
    const float* __restrict__ bias, const float* __restrict__ w5,
    const float* __restrict__ dinv,
    float* __restrict__ y_out, float* __restrict__ zy) {
    __shared__ __align__(16) char smem[65536];
    float (*Afs)[64] = (float (*)[64])smem;                             // [128][64] f32
    unsigned short (*Bh)[64] = (unsigned short (*)[64])(smem + 32768);  // [128][64] bf16
    unsigned short (*Bl)[64] = (unsigned short (*)[64])(smem + 49152);

    const int brow = blockIdx.x * 128, bcol = blockIdx.y * 128;
    const int t = threadIdx.x;
    const int lane = t & 63;
    const int wave = t >> 6;
    const int wm = wave >> 1, wn = wave & 1;
    const int fr = lane & 15;
    const int kq = lane >> 4;

    floatx4 acc[4][4];
#pragma unroll
    for (int i = 0; i < 4; ++i)
#pragma unroll
        for (int j = 0; j < 4; ++j)
            acc[i][j] = (floatx4){0.f, 0.f, 0.f, 0.f};

    const int arow_l = t >> 4;   // 0..15 per pass
    const int aslot  = t & 15;   // 16B slot within 64-f32 row
    const int brow_l = t >> 3;   // 0..31 per pass
    const int bslot  = t & 7;    // 16B slot within 64-bf16 row

    for (int ks = 0; ks < 8; ++ks) {
        const int k0 = ks * 64;
#pragma unroll
        for (int p = 0; p < 8; ++p) {
            int row = p * 16 + arow_l;
            int grow = brow + row;
            int rowc = grow < NNODE ? grow : 0;   // clamp; garbage rows discarded
            int slot = aslot ^ (row & 15);
            const float* ga = A + (size_t)rowc * IND + k0 + slot * 4;
            GLOAD_LDS16(ga, smem + p * 4096 + t * 16);
        }
#pragma unroll
        for (int p = 0; p < 4; ++p) {
            int row = p * 32 + brow_l;            // output-col within tile, < 128
            int slot = bslot ^ (row & 7);
            const unsigned short* gh = WThi + (size_t)(bcol + row) * IND + k0 + slot * 8;
            const unsigned short* gl = WTlo + (size_t)(bcol + row) * IND + k0 + slot * 8;
            GLOAD_LDS16(gh, smem + 32768 + p * 4096 + t * 16);
            GLOAD_LDS16(gl, smem + 49152 + p * 4096 + t * 16);
        }
        __syncthreads();
#pragma unroll
        for (int kk = 0; kk < 2; ++kk) {
            short8 ahi[4], alo[4], bhi[4], blo[4];
#pragma unroll
            for (int i = 0; i < 4; ++i) {
                int r = wm * 64 + i * 16 + fr;
                int s0 = kk * 8 + kq * 2;
                int X = r & 15;
                floatx4 a0 = *(const floatx4*)&Afs[r][(s0 ^ X) * 4];
                floatx4 a1 = *(const floatx4*)&Afs[r][((s0 + 1) ^ X) * 4];
#pragma unroll
                for (int c = 0; c < 4; ++c) {
                    unsigned u0 = __float_as_uint(a0[c]);
                    float h0 = __uint_as_float(u0 & 0xFFFF0000u);
                    ahi[i][c] = (short)(u0 >> 16);
                    alo[i][c] = (short)(__float_as_uint(a0[c] - h0) >> 16);
                    unsigned u1 = __float_as_uint(a1[c]);
                    float h1 = __uint_as_float(u1 & 0xFFFF0000u);
                    ahi[i][c + 4] = (short)(u1 >> 16);
                    alo[i][c + 4] = (short)(__float_as_uint(a1[c] - h1) >> 16);
                }
            }
#pragma unroll
            for (int j = 0; j < 4; ++j) {
                int r = wn * 64 + j * 16 + fr;
                int sb = (kk * 4 + kq) ^ (r & 7);
                bhi[j] = *(const short8*)&Bh[r][sb * 8];
                blo[j] = *(const short8*)&Bl[r][sb * 8];
            }
#pragma unroll
            for (int i = 0; i < 4; ++i)
#pragma unroll
                for (int j = 0; j < 4; ++j) {
                    acc[i][j] = __builtin_amdgcn_mfma_f32_16x16x32_bf16(ahi[i], bhi[j], acc[i][j], 0, 0, 0);
                    acc[i][j] = __builtin_amdgcn_mfma_f32_16x16x32_bf16(ahi[i], blo[j], acc[i][j], 0, 0, 0);
                    acc[i][j] = __builtin_amdgcn_mfma_f32_16x16x32_bf16(alo[i], bhi[j], acc[i][j], 0, 0, 0);
                }
        }
        __syncthreads();
    }

    float w0 = w5[0];
#pragma unroll
    for (int i = 0; i < 4; ++i) {
#pragma unroll
        for (int j = 0; j < 4; ++j) {
            int gcol = bcol + wn * 64 + j * 16 + fr;   // < 256 always
            float bb = bias[gcol];
#pragma unroll
            for (int r = 0; r < 4; ++r) {
                int grow = brow + wm * 64 + i * 16 + kq * 4 + r;
                if (grow < NNODE) {
                    float v = acc[i][j][r] + bb;
                    v = v > 0.0f ? v : 0.01f * v;
                    float y0 = dinv[grow] * v;
                    y_out[(size_t)grow * HD + gcol] = y0;
                    zy[(size_t)grow * HD + gcol] = w0 * y0;
                }
            }
        }
    }
}

// ---------------------------------------------------------------------------
// 6. y-space Laplacian, channel-QUARTERED for per-XCD L2 residency
//    (2.5 MB quarter < 4 MB L2), 16 lanes x float4 per node (1 KB/wave-instr):
//    ynew[v] = y[v] - dinv2[v] * sum_{u in N(v)} y[u];  zy += w_k * ynew
// ---------------------------------------------------------------------------
__global__ __launch_bounds__(256) void lapq_kernel(
    const float* __restrict__ yin, float* __restrict__ yout,
    float* __restrict__ zy, const float* __restrict__ dinv2,
    const int* __restrict__ row_ptr, const int* __restrict__ col,
    const float* __restrict__ w5, int k, int q) {
    const int group = threadIdx.x >> 4;        // 0..15 node-groups
    const int l16 = threadIdx.x & 15;
    const int v = blockIdx.x * 16 + group;     // grid 625 -> v < 10000
    const int c = q * 64 + l16 * 4;
    const float wk = w5[k];
    const int beg = row_ptr[v], end = row_ptr[v + 1];
    floatx4 s = {0.f, 0.f, 0.f, 0.f};
    for (int j = beg; j < end; ++j) {
        int u = col[j];
        floatx4 fv = *(const floatx4*)(yin + (size_t)u * HD + c);
        s[0] += fv[0]; s[1] += fv[1]; s[2] += fv[2]; s[3] += fv[3];
    }
    const float d2 = dinv2[v];
    const size_t idx = (size_t)v * HD + c;
    floatx4 fi = *(const floatx4*)(yin + idx);
    floatx4 o = {fi[0] - d2 * s[0], fi[1] - d2 * s[1],
                 fi[2] - d2 * s[2], fi[3] - d2 * s[3]};
    *(floatx4*)(yout + idx) = o;
    floatx4 rc = *(const floatx4*)(zy + idx);
    rc[0] = fmaf(wk, o[0], rc[0]);
    rc[1] = fmaf(wk, o[1], rc[1]);
    rc[2] = fmaf(wk, o[2], rc[2]);
    rc[3] = fmaf(wk, o[3], rc[3]);
    *(floatx4*)(zy + idx) = rc;
}

// ---------------------------------------------------------------------------
// 6b. last quarter-Laplacian: recons = (zy + w4*ynew)*sqrt(deg), bf16 hi/lo
// ---------------------------------------------------------------------------
__global__ __launch_bounds__(256) void lapq_last_kernel(
    const float* __restrict__ yin, const float* __restrict__ zy,
    const float* __restrict__ dinv2, const float* __restrict__ dsqrt,
    const int* __restrict__ row_ptr, const int* __restrict__ col,
    const float* __restrict__ w5, int q,
    unsigned short* __restrict__ Rhi, unsigned short* __restrict__ Rlo) {
    const int group = threadIdx.x >> 4;
    const int l16 = threadIdx.x & 15;
    const int v = blockIdx.x * 16 + group;
    const int c = q * 64 + l16 * 4;
    const float w4 = w5[4];
    const int beg = row_ptr[v], end = row_ptr[v + 1];
    floatx4 s = {0.f, 0.f, 0.f, 0.f};
    for (int j = beg; j < end; ++j) {
        int u = col[j];
        floatx4 fv = *(const floatx4*)(yin + (size_t)u * HD + c);
        s[0] += fv[0]; s[1] += fv[1]; s[2] += fv[2]; s[3] += fv[3];
    }
    const float d2 = dinv2[v];
    const float ds = dsqrt[v];
    const size_t idx = (size_t)v * HD + c;
    floatx4 fi = *(const floatx4*)(yin + idx);
    floatx4 rc = *(const floatx4*)(zy + idx);
    ushortx4 hi, lo;
#pragma unroll
    for (int cc = 0; cc < 4; ++cc) {
        float ynew = fi[cc] - d2 * s[cc];
        float r = (rc[cc] + w4 * ynew) * ds;
        unsigned u = __float_as_uint(r);
        float hif = __uint_as_float(u & 0xFFFF0000u);
        float lof = r - hif;   // exact (same binade)
        hi[cc] = (unsigned short)(u >> 16);
        lo[cc] = (unsigned short)(__float_as_uint(lof) >> 16);
    }
    *(ushortx4*)(Rhi + idx) = hi;
    *(ushortx4*)(Rlo + idx) = lo;
}

// ---------------------------------------------------------------------------
// 7. GEMM2 (MFMA): out = sigmoid(R R^T), 128x128 lower-triangle blocks in
//    supertile order (tab), LDS-staged full-line NT writes, light barriers.
// ---------------------------------------------------------------------------
__global__ __launch_bounds__(256) void gemm2_mfma(
    const unsigned short* __restrict__ Rhi,
    const unsigned short* __restrict__ Rlo,
    const int* __restrict__ tab,
    float* __restrict__ out) {
    __shared__ __align__(16) char smem[32768];
    unsigned short (*As)[64] = (unsigned short (*)[64])smem;
    unsigned short (*Bs)[64] = (unsigned short (*)[64])(smem + 16384);

    const int orig = blockIdx.x;
    const int kb = (orig & 7) * (NTRI / 8) + (orig >> 3);
    const int e = tab[kb];
    const int bi = e >> 16, bj = e & 0xffff;
    const int brow = bi * 128, bcol = bj * 128;

    const int t = threadIdx.x;
    const int lane = t & 63;
    const int wave = t >> 6;
    const int wm = wave >> 1, wn = wave & 1;
    const int fr = lane & 15;
    const int kq = lane >> 4;

    floatx4 acc[4][4];
#pragma unroll
    for (int i = 0; i < 4; ++i)
#pragma unroll
        for (int j = 0; j < 4; ++j)
            acc[i][j] = (floatx4){0.f, 0.f, 0.f, 0.f};

    const int srow = t >> 3;
    const int scol = (t & 7) * 8;

    for (int ks = 0; ks < 12; ++ks) {
        const int seg = ks >> 2;
        const int k0 = (ks & 3) * 64;
        const unsigned short* Aseg = (seg < 2) ? Rhi : Rlo;
        const unsigned short* Bseg = (seg == 1) ? Rlo : Rhi;
#pragma unroll
        for (int p = 0; p < 4; ++p) {
            const unsigned short* ga = Aseg + (size_t)(brow + p * 32 + srow) * HD + k0 + scol;
            const unsigned short* gb = Bseg + (size_t)(bcol + p * 32 + srow) * HD + k0 + scol;
            GLOAD_LDS16(ga, (unsigned short*)smem + p * 2048 + t * 8);
            GLOAD_LDS16(gb, (unsigned short*)smem + 8192 + p * 2048 + t * 8);
        }
        __syncthreads();
#pragma unroll
        for (int kk = 0; kk < 2; ++kk) {
            short8 a[4], b[4];
#pragma unroll
            for (int i = 0; i < 4; ++i)
                a[i] = *(const short8*)&As[wm * 64 + i * 16 + fr][kk * 32 + kq * 8];
#pragma unroll
            for (int j = 0; j < 4; ++j)
                b[j] = *(const short8*)&Bs[wn * 64 + j * 16 + fr][kk * 32 + kq * 8];
#pragma unroll
            for (int i = 0; i < 4; ++i)
#pragma unroll
                for (int j = 0; j < 4; ++j)
                    acc[i][j] = __builtin_amdgcn_mfma_f32_16x16x32_bf16(
                        a[i], b[j], acc[i][j], 0, 0, 0);
        }
        __syncthreads();
    }

    const int tr = t >> 3, tl = t & 7;

    // --- direct tile: stage 32-row chunks in LDS, full-line NT writes ---
    {
        float (*sd)[132] = (float (*)[132])smem;
        const int cmaxd = NNODE - bcol;
#pragma unroll
        for (int c0 = 0; c0 < 128; c0 += 32) {
            if (wm == (c0 >> 6)) {
                int ibase = (c0 & 63) >> 4;
#pragma unroll
                for (int ii = 0; ii < 2; ++ii) {
                    int i = ibase + ii;
#pragma unroll
                    for (int j = 0; j < 4; ++j)
#pragma unroll
                        for (int r = 0; r < 4; ++r) {
                            float s = 1.0f / (1.0f + __expf(-acc[i][j][r]));
                            sd[ii * 16 + kq * 4 + r][wn * 64 + j * 16 + fr] = s;
                        }
                }
            }
            LIGHT_BARRIER();
            int grow = brow + c0 + tr;
            if (grow < NNODE) {
                float* orow = out + (size_t)grow * NNODE + bcol;
#pragma unroll
                for (int k = 0; k < 4; ++k) {
                    int x = tl * 4 + k * 32;
                    if (x + 4 <= cmaxd) {
                        floatx4 v = {sd[tr][x], sd[tr][x + 1], sd[tr][x + 2], sd[tr][x + 3]};
                        __builtin_nontemporal_store(v, (floatx4*)(orow + x));
                    } else {
                        for (int xx = x; xx < cmaxd && xx < x + 4; ++xx)
                            __builtin_nontemporal_store(sd[tr][xx], orow + xx);
                    }
                }
            }
            LIGHT_BARRIER();
        }
    }

    // --- mirror tile via LDS transpose (skip diagonal) ---
    if (bi == bj) return;
    {
        float (*trs)[129] = (float (*)[129])smem;
        const int cmax = NNODE - brow;
#pragma unroll
        for (int c0 = 0; c0 < 128; c0 += 32) {
            if (wn == (c0 >> 6)) {
                int jlo = (c0 & 63) >> 4;
#pragma unroll
                for (int jj = 0; jj < 2; ++jj) {
                    int j = jlo + jj;
#pragma unroll
                    for (int i = 0; i < 4; ++i)
#pragma unroll
                        for (int r = 0; r < 4; ++r) {
                            float s = 1.0f / (1.0f + __expf(-acc[i][j][r]));
                            trs[jj * 16 + fr][wm * 64 + i * 16 + kq * 4 + r] = s;
                        }
                }
            }
            LIGHT_BARRIER();
            int gr = bcol + c0 + tr;   // < NNODE (bj < bi)
            float* orow = out + (size_t)gr * NNODE + brow;
#pragma unroll
            for (int k = 0; k < 4; ++k) {
                int x = tl * 4 + k * 32;
                if (x + 4 <= cmax) {
                    floatx4 v = {trs[tr][x], trs[tr][x + 1], trs[tr][x + 2], trs[tr][x + 3]};
                    __builtin_nontemporal_store(v, (floatx4*)(orow + x));
                } else {
                    for (int xx = x; xx < cmax && xx < x + 4; ++xx)
                        __builtin_nontemporal_store(trs[tr][xx], orow + xx);
                }
            }
            LIGHT_BARRIER();
        }
    }
}

// ---------------------------------------------------------------------------
extern "C" void kernel_launch(void* const* d_in, const int* in_sizes, int n_in,
                              void* d_out, int out_size, void* d_ws, size_t ws_size,
                              hipStream_t stream) {
    const float* in_feat = (const float*)d_in[0];
    const float* W       = (const float*)d_in[1];
    const float* bias    = (const float*)d_in[2];
    const float* lam     = (const float*)d_in[3];
    const int*   src     = (const int*)d_in[4];
    const int*   dst     = (const int*)d_in[5];
    const int    E       = in_sizes[4];
    float* out = (float*)d_out;

    char* p = (char*)d_ws;
    auto alloc = [&](size_t bytes) -> void* {
        void* r = (void*)p;
        p += (bytes + 255) & ~(size_t)255;
        return r;
    };
    int*   cnts    = (int*)alloc(3 * NNODE * sizeof(int));
    int*   cnt_src = cnts;
    int*   cnt_dst = cnts + NNODE;
    int*   cursor  = cnts + 2 * NNODE;
    int*   row_ptr = (int*)alloc((NNODE + 1) * sizeof(int));
    int*   col     = (int*)alloc((size_t)E * sizeof(int));
    float* dinv    = (float*)alloc(NNODE * sizeof(float));
    float* dinv2   = (float*)alloc(NNODE * sizeof(float));
    float* dsqrt   = (float*)alloc(NNODE * sizeof(float));
    float* w5      = (float*)alloc(8 * sizeof(float));
    int*   tab     = (int*)alloc(NTRI * sizeof(int));
    float* y_a     = (float*)alloc((size_t)NNODE * HD * sizeof(float));
    float* y_b     = (float*)alloc((size_t)NNODE * HD * sizeof(float));
    float* zy      = (float*)alloc((size_t)NNODE * HD * sizeof(float));
    unsigned short* Rhi  = (unsigned short*)alloc((size_t)PAD_M * HD * sizeof(unsigned short));
    unsigned short* Rlo  = (unsigned short*)alloc((size_t)PAD_M * HD * sizeof(unsigned short));
    unsigned short* WThi = (unsigned short*)alloc((size_t)HD * IND * sizeof(unsigned short));
    unsigned short* WTlo = (unsigned short*)alloc((size_t)HD * IND * sizeof(unsigned short));

    hipMemsetAsync(cnts, 0, 3 * NNODE * sizeof(int), stream);
    hipMemsetAsync(Rhi + (size_t)NNODE * HD, 0, (size_t)(PAD_M - NNODE) * HD * 2, stream);
    hipMemsetAsync(Rlo + (size_t)NNODE * HD, 0, (size_t)(PAD_M - NNODE) * HD * 2, stream);

    int eb = (E + 255) / 256;
    count_kernel<<<eb, 256, 0, stream>>>(src, dst, E, cnt_src, cnt_dst);
    w_kernel<<<1, 64, 0, stream>>>(lam, w5);
    order_kernel<<<1, 64, 0, stream>>>(tab);
    scan_kernel<<<1, 1024, 0, stream>>>(cnt_src, cnt_dst, dinv, dinv2, dsqrt, row_ptr);
    fill_kernel<<<eb, 256, 0, stream>>>(src, dst, E, row_ptr, cursor, col);

    split_wt_kernel<<<(IND * HD + 255) / 256, 256, 0, stream>>>(W, WThi, WTlo);

    dim3 g1(NTILE, HD / 128);
    gemm1_mfma<<<g1, 256, 0, stream>>>(in_feat, WThi, WTlo, bias, w5, dinv, y_a, zy);

    // quartered y-space lap chain: quarter outer (L2-resident), lap inner
    for (int q = 0; q < 4; ++q) {
        lapq_kernel<<<NNODE / 16, 256, 0, stream>>>(y_a, y_b, zy, dinv2, row_ptr, col, w5, 1, q);
        lapq_kernel<<<NNODE / 16, 256, 0, stream>>>(y_b, y_a, zy, dinv2, row_ptr, col, w5, 2, q);
        lapq_kernel<<<NNODE / 16, 256, 0, stream>>>(y_a, y_b, zy, dinv2, row_ptr, col, w5, 3, q);
        lapq_last_kernel<<<NNODE / 16, 256, 0, stream>>>(y_b, zy, dinv2, dsqrt, row_ptr, col, w5, q, Rhi, Rlo);
    }

    gemm2_mfma<<<NTRI, 256, 0, stream>>>(Rhi, Rlo, tab, out);
}

// Round 12
// 562.667 us; speedup vs baseline: 1.2160x; 1.2160x over previous
//
#include <hip/hip_runtime.h>
#include <cstddef>

#define NNODE 10000
#define IND 512
#define HD 256
#define PAD_M 10112    // 79 * 128
#define NTILE 79
#define NTRI (NTILE * (NTILE + 1) / 2)   // 3160 lower-triangle blocks
#define NST ((NTILE + 7) / 8)            // 10 row-supertiles

typedef __attribute__((ext_vector_type(8))) short short8;
typedef __attribute__((ext_vector_type(4))) float floatx4;
typedef __attribute__((ext_vector_type(4))) unsigned short ushortx4;

#define GLOAD_LDS16(gp, lp) __builtin_amdgcn_global_load_lds( \
    (const __attribute__((address_space(1))) unsigned int*)(gp), \
    (__attribute__((address_space(3))) unsigned int*)(lp), 16, 0, 0)

// barrier that waits only on LDS ops (lgkmcnt), NOT on outstanding stores
#define LIGHT_BARRIER() do { \
    asm volatile("s_waitcnt lgkmcnt(0)" ::: "memory"); \
    __builtin_amdgcn_s_barrier(); \
} while (0)

// ---------------------------------------------------------------------------
// 1. count degrees
// ---------------------------------------------------------------------------
__global__ void count_kernel(const int* __restrict__ src, const int* __restrict__ dst,
                             int E, int* __restrict__ cnt_src, int* __restrict__ cnt_dst) {
    int e = blockIdx.x * blockDim.x + threadIdx.x;
    if (e < E) {
        atomicAdd(&cnt_src[src[e]], 1);
        atomicAdd(&cnt_dst[dst[e]], 1);
    }
}

// ---------------------------------------------------------------------------
// 2. dinv, dinv^2, sqrt(deg) + exclusive scan of cnt_dst -> row_ptr
// ---------------------------------------------------------------------------
__global__ __launch_bounds__(1024) void scan_kernel(const int* __restrict__ cnt_src,
                                                    const int* __restrict__ cnt_dst,
                                                    float* __restrict__ dinv,
                                                    float* __restrict__ dinv2,
                                                    float* __restrict__ dsqrt,
                                                    int* __restrict__ row_ptr) {
    int t = threadIdx.x;
    for (int i = t; i < NNODE; i += 1024) {
        float d = fmaxf((float)cnt_src[i], 1.0f);
        float di = rsqrtf(d);
        dinv[i] = di;
        dinv2[i] = di * di;
        dsqrt[i] = sqrtf(d);
    }

    __shared__ int sums[1024];
    const int CH = (NNODE + 1023) / 1024;  // 10
    int base = t * CH;
    int s = 0;
    for (int i = 0; i < CH; ++i) {
        int idx = base + i;
        if (idx < NNODE) s += cnt_dst[idx];
    }
    sums[t] = s;
    __syncthreads();
    for (int off = 1; off < 1024; off <<= 1) {
        int v = (t >= off) ? sums[t - off] : 0;
        __syncthreads();
        sums[t] += v;
        __syncthreads();
    }
    int run = (t == 0) ? 0 : sums[t - 1];
    for (int i = 0; i < CH; ++i) {
        int idx = base + i;
        if (idx < NNODE) { row_ptr[idx] = run; run += cnt_dst[idx]; }
    }
    if (t == 1023) row_ptr[NNODE] = sums[1023];
}

// ---------------------------------------------------------------------------
// 3. fill CSR (by dst)
// ---------------------------------------------------------------------------
__global__ void fill_kernel(const int* __restrict__ src, const int* __restrict__ dst,
                            int E, const int* __restrict__ row_ptr,
                            int* __restrict__ cursor, int* __restrict__ col) {
    int e = blockIdx.x * blockDim.x + threadIdx.x;
    if (e < E) {
        int v = dst[e];
        int pos = row_ptr[v] + atomicAdd(&cursor[v], 1);
        col[pos] = src[e];
    }
}

// ---------------------------------------------------------------------------
// 3b. supertile-ordered (bi,bj) table for gemm2 (8x8-block supertiles)
// ---------------------------------------------------------------------------
__global__ void order_kernel(int* __restrict__ tab) {
    int s = threadIdx.x;                 // supertile id, 0..54
    if (s >= NST * (NST + 1) / 2) return;
    int I = 0;
    while ((I + 1) * (I + 2) / 2 <= s) ++I;
    int J = s - I * (I + 1) / 2;
    auto cnt = [](int Ii, int Jj) {
        int r0 = Ii * 8, r1 = min(r0 + 8, NTILE);
        int c = 0;
        for (int bi = r0; bi < r1; ++bi) {
            int c0 = Jj * 8, c1 = min(min(c0 + 8, NTILE), bi + 1);
            c += max(0, c1 - c0);
        }
        return c;
    };
    int off = 0;
    for (int sp = 0; sp < s; ++sp) {
        int Ip = 0;
        while ((Ip + 1) * (Ip + 2) / 2 <= sp) ++Ip;
        int Jp = sp - Ip * (Ip + 1) / 2;
        off += cnt(Ip, Jp);
    }
    int r0 = I * 8, r1 = min(r0 + 8, NTILE);
    for (int bi = r0; bi < r1; ++bi) {
        int c0 = J * 8, c1 = min(min(c0 + 8, NTILE), bi + 1);
        for (int bj = c0; bj < c1; ++bj)
            tab[off++] = (bi << 16) | bj;
    }
}

// ---------------------------------------------------------------------------
// 4. combine weights w_k
// ---------------------------------------------------------------------------
__global__ void w_kernel(const float* __restrict__ lam, float* __restrict__ w) {
    if (threadIdx.x == 0 && blockIdx.x == 0) {
        float c[5];
        float s0 = 1.0f / (1.0f + expf(-lam[0]));
        c[0] = s0;
        c[1] = s0;  // reference reuses lam[0] for all_h[1]
        c[2] = 1.0f / (1.0f + expf(-lam[1]));
        c[3] = 1.0f / (1.0f + expf(-lam[2]));
        c[4] = 1.0f / (1.0f + expf(-lam[3]));
        const float TH[5][5] = {
            {5.0f, -10.0f,  7.5f, -2.5f, 0.3125f},
            {0.0f,  10.0f, -15.0f, 7.5f, -1.25f },
            {0.0f,   0.0f,  7.5f, -7.5f, 1.875f },
            {0.0f,   0.0f,  0.0f,  2.5f, -1.25f },
            {0.0f,   0.0f,  0.0f,  0.0f, 0.3125f}};
        for (int k = 0; k < 5; ++k) {
            float acc = 0.0f;
            for (int i = 0; i < 5; ++i) acc += c[i] * TH[i][k];
            w[k] = acc;
        }
    }
}

// ---------------------------------------------------------------------------
// 4c. split + transpose W -> WT [HD][IND] bf16 hi/lo
// ---------------------------------------------------------------------------
__global__ void split_wt_kernel(const float* __restrict__ W,
                                unsigned short* __restrict__ WThi,
                                unsigned short* __restrict__ WTlo) {
    int tid = blockIdx.x * blockDim.x + threadIdx.x;  // 0 .. IND*HD-1
    if (tid >= IND * HD) return;
    int n = tid & (HD - 1);
    int k = tid >> 8;
    float r = W[(size_t)k * HD + n];
    unsigned u = __float_as_uint(r);
    float hif = __uint_as_float(u & 0xFFFF0000u);
    float lof = r - hif;
    WThi[(size_t)n * IND + k] = (unsigned short)(u >> 16);
    WTlo[(size_t)n * IND + k] = (unsigned short)(__float_as_uint(lof) >> 16);
}

// ---------------------------------------------------------------------------
// 5. GEMM1 (MFMA, fused in-register hi/lo split of f32 A):
//    h = leaky_relu(in_feat @ W + b); y0 = dinv*h; zy = w0*y0.
// ---------------------------------------------------------------------------
__global__ __launch_bounds__(256) void gemm1_mfma(
    const float* __restrict__ A,
    const unsigned short* __restrict__ WThi, const unsigned short* __restrict__ WTlo,
    const float* __restrict__ bias, const float* __restrict__ w5,
    const float* __restrict__ dinv,
    float* __restrict__ y_out, float* __restrict__ zy) {
    __shared__ __align__(16) char smem[65536];
    float (*Afs)[64] = (float (*)[64])smem;                             // [128][64] f32
    unsigned short (*Bh)[64] = (unsigned short (*)[64])(smem + 32768);  // [128][64] bf16
    unsigned short (*Bl)[64] = (unsigned short (*)[64])(smem + 49152);

    const int brow = blockIdx.x * 128, bcol = blockIdx.y * 128;
    const int t = threadIdx.x;
    const int lane = t & 63;
    const int wave = t >> 6;
    const int wm = wave >> 1, wn = wave & 1;
    const int fr = lane & 15;
    const int kq = lane >> 4;

    floatx4 acc[4][4];
#pragma unroll
    for (int i = 0; i < 4; ++i)
#pragma unroll
        for (int j = 0; j < 4; ++j)
            acc[i][j] = (floatx4){0.f, 0.f, 0.f, 0.f};

    const int arow_l = t >> 4;   // 0..15 per pass
    const int aslot  = t & 15;   // 16B slot within 64-f32 row
    const int brow_l = t >> 3;   // 0..31 per pass
    const int bslot  = t & 7;    // 16B slot within 64-bf16 row

    for (int ks = 0; ks < 8; ++ks) {
        const int k0 = ks * 64;
#pragma unroll
        for (int p = 0; p < 8; ++p) {
            int row = p * 16 + arow_l;
            int grow = brow + row;
            int rowc = grow < NNODE ? grow : 0;   // clamp; garbage rows discarded
            int slot = aslot ^ (row & 15);
            const float* ga = A + (size_t)rowc * IND + k0 + slot * 4;
            GLOAD_LDS16(ga, smem + p * 4096 + t * 16);
        }
#pragma unroll
        for (int p = 0; p < 4; ++p) {
            int row = p * 32 + brow_l;            // output-col within tile, < 128
            int slot = bslot ^ (row & 7);
            const unsigned short* gh = WThi + (size_t)(bcol + row) * IND + k0 + slot * 8;
            const unsigned short* gl = WTlo + (size_t)(bcol + row) * IND + k0 + slot * 8;
            GLOAD_LDS16(gh, smem + 32768 + p * 4096 + t * 16);
            GLOAD_LDS16(gl, smem + 49152 + p * 4096 + t * 16);
        }
        __syncthreads();
#pragma unroll
        for (int kk = 0; kk < 2; ++kk) {
            short8 ahi[4], alo[4], bhi[4], blo[4];
#pragma unroll
            for (int i = 0; i < 4; ++i) {
                int r = wm * 64 + i * 16 + fr;
                int s0 = kk * 8 + kq * 2;
                int X = r & 15;
                floatx4 a0 = *(const floatx4*)&Afs[r][(s0 ^ X) * 4];
                floatx4 a1 = *(const floatx4*)&Afs[r][((s0 + 1) ^ X) * 4];
#pragma unroll
                for (int c = 0; c < 4; ++c) {
                    unsigned u0 = __float_as_uint(a0[c]);
                    float h0 = __uint_as_float(u0 & 0xFFFF0000u);
                    ahi[i][c] = (short)(u0 >> 16);
                    alo[i][c] = (short)(__float_as_uint(a0[c] - h0) >> 16);
                    unsigned u1 = __float_as_uint(a1[c]);
                    float h1 = __uint_as_float(u1 & 0xFFFF0000u);
                    ahi[i][c + 4] = (short)(u1 >> 16);
                    alo[i][c + 4] = (short)(__float_as_uint(a1[c] - h1) >> 16);
                }
            }
#pragma unroll
            for (int j = 0; j < 4; ++j) {
                int r = wn * 64 + j * 16 + fr;
                int sb = (kk * 4 + kq) ^ (r & 7);
                bhi[j] = *(const short8*)&Bh[r][sb * 8];
                blo[j] = *(const short8*)&Bl[r][sb * 8];
            }
#pragma unroll
            for (int i = 0; i < 4; ++i)
#pragma unroll
                for (int j = 0; j < 4; ++j) {
                    acc[i][j] = __builtin_amdgcn_mfma_f32_16x16x32_bf16(ahi[i], bhi[j], acc[i][j], 0, 0, 0);
                    acc[i][j] = __builtin_amdgcn_mfma_f32_16x16x32_bf16(ahi[i], blo[j], acc[i][j], 0, 0, 0);
                    acc[i][j] = __builtin_amdgcn_mfma_f32_16x16x32_bf16(alo[i], bhi[j], acc[i][j], 0, 0, 0);
                }
        }
        __syncthreads();
    }

    float w0 = w5[0];
#pragma unroll
    for (int i = 0; i < 4; ++i) {
#pragma unroll
        for (int j = 0; j < 4; ++j) {
            int gcol = bcol + wn * 64 + j * 16 + fr;   // < 256 always
            float bb = bias[gcol];
#pragma unroll
            for (int r = 0; r < 4; ++r) {
                int grow = brow + wm * 64 + i * 16 + kq * 4 + r;
                if (grow < NNODE) {
                    float v = acc[i][j][r] + bb;
                    v = v > 0.0f ? v : 0.01f * v;
                    float y0 = dinv[grow] * v;
                    y_out[(size_t)grow * HD + gcol] = y0;
                    zy[(size_t)grow * HD + gcol] = w0 * y0;
                }
            }
        }
    }
}

// ---------------------------------------------------------------------------
// 6. y-space Laplacian, full 256 channels, float4/lane (R8/R10 structure):
//    ynew[v] = y[v] - dinv2[v] * sum_{u in N(v)} y[u];  zy += w_k * ynew
// ---------------------------------------------------------------------------
__global__ __launch_bounds__(256) void lap_kernel(
    const float* __restrict__ yin, float* __restrict__ yout,
    float* __restrict__ zy, const float* __restrict__ dinv2,
    const int* __restrict__ row_ptr, const int* __restrict__ col,
    const float* __restrict__ w5, int k) {
    const int g = threadIdx.x >> 6;
    const int lane = threadIdx.x & 63;
    const int v = blockIdx.x * 4 + g;
    if (v >= NNODE) return;
    const float wk = w5[k];
    const int beg = row_ptr[v], end = row_ptr[v + 1];
    float s0 = 0.f, s1 = 0.f, s2 = 0.f, s3 = 0.f;
    const size_t coff = (size_t)lane * 4;
    for (int j = beg; j < end; ++j) {
        int u = col[j];
        floatx4 fv = *(const floatx4*)(yin + (size_t)u * HD + coff);
        s0 += fv[0];
        s1 += fv[1];
        s2 += fv[2];
        s3 += fv[3];
    }
    const float d2 = dinv2[v];
    const size_t idx = (size_t)v * HD + coff;
    floatx4 fi = *(const floatx4*)(yin + idx);
    floatx4 o = {fi[0] - d2 * s0, fi[1] - d2 * s1, fi[2] - d2 * s2, fi[3] - d2 * s3};
    *(floatx4*)(yout + idx) = o;
    floatx4 rc = *(const floatx4*)(zy + idx);
    rc[0] = fmaf(wk, o[0], rc[0]);
    rc[1] = fmaf(wk, o[1], rc[1]);
    rc[2] = fmaf(wk, o[2], rc[2]);
    rc[3] = fmaf(wk, o[3], rc[3]);
    *(floatx4*)(zy + idx) = rc;
}

// ---------------------------------------------------------------------------
// 6b. last y-space Laplacian: recons = (zy + w4*ynew)*sqrt(deg), bf16 hi/lo
// ---------------------------------------------------------------------------
__global__ __launch_bounds__(256) void lap_last_kernel(
    const float* __restrict__ yin, const float* __restrict__ zy,
    const float* __restrict__ dinv2, const float* __restrict__ dsqrt,
    const int* __restrict__ row_ptr, const int* __restrict__ col,
    const float* __restrict__ w5,
    unsigned short* __restrict__ Rhi, unsigned short* __restrict__ Rlo) {
    const int g = threadIdx.x >> 6;
    const int lane = threadIdx.x & 63;
    const int v = blockIdx.x * 4 + g;
    if (v >= NNODE) return;
    const float w4 = w5[4];
    const int beg = row_ptr[v], end = row_ptr[v + 1];
    float s0 = 0.f, s1 = 0.f, s2 = 0.f, s3 = 0.f;
    const size_t coff = (size_t)lane * 4;
    for (int j = beg; j < end; ++j) {
        int u = col[j];
        floatx4 fv = *(const floatx4*)(yin + (size_t)u * HD + coff);
        s0 += fv[0];
        s1 += fv[1];
        s2 += fv[2];
        s3 += fv[3];
    }
    const float d2 = dinv2[v];
    const float ds = dsqrt[v];
    const size_t idx = (size_t)v * HD + coff;
    floatx4 fi = *(const floatx4*)(yin + idx);
    floatx4 rc = *(const floatx4*)(zy + idx);
    float ss[4] = {s0, s1, s2, s3};
    ushortx4 hi, lo;
#pragma unroll
    for (int c = 0; c < 4; ++c) {
        float ynew = fi[c] - d2 * ss[c];
        float r = (rc[c] + w4 * ynew) * ds;
        unsigned u = __float_as_uint(r);
        float hif = __uint_as_float(u & 0xFFFF0000u);
        float lof = r - hif;   // exact (same binade)
        hi[c] = (unsigned short)(u >> 16);
        lo[c] = (unsigned short)(__float_as_uint(lof) >> 16);
    }
    *(ushortx4*)(Rhi + idx) = hi;
    *(ushortx4*)(Rlo + idx) = lo;
}

// ---------------------------------------------------------------------------
// 7. GEMM2 (MFMA): out = sigmoid(R R^T), 128x128 lower-triangle blocks in
//    supertile order (tab), LDS-staged full-line CACHED writes (NT removed:
//    with supertile ordering the panel set is ~2 MB/XCD, so L2 write-combine
//    outweighs eviction risk; NT stores were capping the stream at ~2.4 TB/s).
// ---------------------------------------------------------------------------
__global__ __launch_bounds__(256) void gemm2_mfma(
    const unsigned short* __restrict__ Rhi,
    const unsigned short* __restrict__ Rlo,
    const int* __restrict__ tab,
    float* __restrict__ out) {
    __shared__ __align__(16) char smem[32768];
    unsigned short (*As)[64] = (unsigned short (*)[64])smem;
    unsigned short (*Bs)[64] = (unsigned short (*)[64])(smem + 16384);

    const int orig = blockIdx.x;
    const int kb = (orig & 7) * (NTRI / 8) + (orig >> 3);
    const int e = tab[kb];
    const int bi = e >> 16, bj = e & 0xffff;
    const int brow = bi * 128, bcol = bj * 128;

    const int t = threadIdx.x;
    const int lane = t & 63;
    const int wave = t >> 6;
    const int wm = wave >> 1, wn = wave & 1;
    const int fr = lane & 15;
    const int kq = lane >> 4;

    floatx4 acc[4][4];
#pragma unroll
    for (int i = 0; i < 4; ++i)
#pragma unroll
        for (int j = 0; j < 4; ++j)
            acc[i][j] = (floatx4){0.f, 0.f, 0.f, 0.f};

    const int srow = t >> 3;
    const int scol = (t & 7) * 8;

    for (int ks = 0; ks < 12; ++ks) {
        const int seg = ks >> 2;
        const int k0 = (ks & 3) * 64;
        const unsigned short* Aseg = (seg < 2) ? Rhi : Rlo;
        const unsigned short* Bseg = (seg == 1) ? Rlo : Rhi;
#pragma unroll
        for (int p = 0; p < 4; ++p) {
            const unsigned short* ga = Aseg + (size_t)(brow + p * 32 + srow) * HD + k0 + scol;
            const unsigned short* gb = Bseg + (size_t)(bcol + p * 32 + srow) * HD + k0 + scol;
            GLOAD_LDS16(ga, (unsigned short*)smem + p * 2048 + t * 8);
            GLOAD_LDS16(gb, (unsigned short*)smem + 8192 + p * 2048 + t * 8);
        }
        __syncthreads();
#pragma unroll
        for (int kk = 0; kk < 2; ++kk) {
            short8 a[4], b[4];
#pragma unroll
            for (int i = 0; i < 4; ++i)
                a[i] = *(const short8*)&As[wm * 64 + i * 16 + fr][kk * 32 + kq * 8];
#pragma unroll
            for (int j = 0; j < 4; ++j)
                b[j] = *(const short8*)&Bs[wn * 64 + j * 16 + fr][kk * 32 + kq * 8];
#pragma unroll
            for (int i = 0; i < 4; ++i)
#pragma unroll
                for (int j = 0; j < 4; ++j)
                    acc[i][j] = __builtin_amdgcn_mfma_f32_16x16x32_bf16(
                        a[i], b[j], acc[i][j], 0, 0, 0);
        }
        __syncthreads();
    }

    const int tr = t >> 3, tl = t & 7;

    // --- direct tile: stage 32-row chunks in LDS, full-line cached writes ---
    {
        float (*sd)[132] = (float (*)[132])smem;
        const int cmaxd = NNODE - bcol;
#pragma unroll
        for (int c0 = 0; c0 < 128; c0 += 32) {
            if (wm == (c0 >> 6)) {
                int ibase = (c0 & 63) >> 4;
#pragma unroll
                for (int ii = 0; ii < 2; ++ii) {
                    int i = ibase + ii;
#pragma unroll
                    for (int j = 0; j < 4; ++j)
#pragma unroll
                        for (int r = 0; r < 4; ++r) {
                            float s = 1.0f / (1.0f + __expf(-acc[i][j][r]));
                            sd[ii * 16 + kq * 4 + r][wn * 64 + j * 16 + fr] = s;
                        }
                }
            }
            LIGHT_BARRIER();
            int grow = brow + c0 + tr;
            if (grow < NNODE) {
                float* orow = out + (size_t)grow * NNODE + bcol;
#pragma unroll
                for (int k = 0; k < 4; ++k) {
                    int x = tl * 4 + k * 32;
                    if (x + 4 <= cmaxd) {
                        floatx4 v = {sd[tr][x], sd[tr][x + 1], sd[tr][x + 2], sd[tr][x + 3]};
                        *(floatx4*)(orow + x) = v;
                    } else {
                        for (int xx = x; xx < cmaxd && xx < x + 4; ++xx)
                            orow[xx] = sd[tr][xx];
                    }
                }
            }
            LIGHT_BARRIER();
        }
    }

    // --- mirror tile via LDS transpose (skip diagonal) ---
    if (bi == bj) return;
    {
        float (*trs)[129] = (float (*)[129])smem;
        const int cmax = NNODE - brow;
#pragma unroll
        for (int c0 = 0; c0 < 128; c0 += 32) {
            if (wn == (c0 >> 6)) {
                int jlo = (c0 & 63) >> 4;
#pragma unroll
                for (int jj = 0; jj < 2; ++jj) {
                    int j = jlo + jj;
#pragma unroll
                    for (int i = 0; i < 4; ++i)
#pragma unroll
                        for (int r = 0; r < 4; ++r) {
                            float s = 1.0f / (1.0f + __expf(-acc[i][j][r]));
                            trs[jj * 16 + fr][wm * 64 + i * 16 + kq * 4 + r] = s;
                        }
                }
            }
            LIGHT_BARRIER();
            int gr = bcol + c0 + tr;   // < NNODE (bj < bi)
            float* orow = out + (size_t)gr * NNODE + brow;
#pragma unroll
            for (int k = 0; k < 4; ++k) {
                int x = tl * 4 + k * 32;
                if (x + 4 <= cmax) {
                    floatx4 v = {trs[tr][x], trs[tr][x + 1], trs[tr][x + 2], trs[tr][x + 3]};
                    *(floatx4*)(orow + x) = v;
                } else {
                    for (int xx = x; xx < cmax && xx < x + 4; ++xx)
                        orow[xx] = trs[tr][xx];
                }
            }
            LIGHT_BARRIER();
        }
    }
}

// ---------------------------------------------------------------------------
extern "C" void kernel_launch(void* const* d_in, const int* in_sizes, int n_in,
                              void* d_out, int out_size, void* d_ws, size_t ws_size,
                              hipStream_t stream) {
    const float* in_feat = (const float*)d_in[0];
    const float* W       = (const float*)d_in[1];
    const float* bias    = (const float*)d_in[2];
    const float* lam     = (const float*)d_in[3];
    const int*   src     = (const int*)d_in[4];
    const int*   dst     = (const int*)d_in[5];
    const int    E       = in_sizes[4];
    float* out = (float*)d_out;

    char* p = (char*)d_ws;
    auto alloc = [&](size_t bytes) -> void* {
        void* r = (void*)p;
        p += (bytes + 255) & ~(size_t)255;
        return r;
    };
    int*   cnts    = (int*)alloc(3 * NNODE * sizeof(int));
    int*   cnt_src = cnts;
    int*   cnt_dst = cnts + NNODE;
    int*   cursor  = cnts + 2 * NNODE;
    int*   row_ptr = (int*)alloc((NNODE + 1) * sizeof(int));
    int*   col     = (int*)alloc((size_t)E * sizeof(int));
    float* dinv    = (float*)alloc(NNODE * sizeof(float));
    float* dinv2   = (float*)alloc(NNODE * sizeof(float));
    float* dsqrt   = (float*)alloc(NNODE * sizeof(float));
    float* w5      = (float*)alloc(8 * sizeof(float));
    int*   tab     = (int*)alloc(NTRI * sizeof(int));
    float* y_a     = (float*)alloc((size_t)NNODE * HD * sizeof(float));
    float* y_b     = (float*)alloc((size_t)NNODE * HD * sizeof(float));
    float* zy      = (float*)alloc((size_t)NNODE * HD * sizeof(float));
    unsigned short* Rhi  = (unsigned short*)alloc((size_t)PAD_M * HD * sizeof(unsigned short));
    unsigned short* Rlo  = (unsigned short*)alloc((size_t)PAD_M * HD * sizeof(unsigned short));
    unsigned short* WThi = (unsigned short*)alloc((size_t)HD * IND * sizeof(unsigned short));
    unsigned short* WTlo = (unsigned short*)alloc((size_t)HD * IND * sizeof(unsigned short));

    hipMemsetAsync(cnts, 0, 3 * NNODE * sizeof(int), stream);
    hipMemsetAsync(Rhi + (size_t)NNODE * HD, 0, (size_t)(PAD_M - NNODE) * HD * 2, stream);
    hipMemsetAsync(Rlo + (size_t)NNODE * HD, 0, (size_t)(PAD_M - NNODE) * HD * 2, stream);

    int eb = (E + 255) / 256;
    count_kernel<<<eb, 256, 0, stream>>>(src, dst, E, cnt_src, cnt_dst);
    w_kernel<<<1, 64, 0, stream>>>(lam, w5);
    order_kernel<<<1, 64, 0, stream>>>(tab);
    scan_kernel<<<1, 1024, 0, stream>>>(cnt_src, cnt_dst, dinv, dinv2, dsqrt, row_ptr);
    fill_kernel<<<eb, 256, 0, stream>>>(src, dst, E, row_ptr, cursor, col);

    split_wt_kernel<<<(IND * HD + 255) / 256, 256, 0, stream>>>(W, WThi, WTlo);

    dim3 g1(NTILE, HD / 128);
    gemm1_mfma<<<g1, 256, 0, stream>>>(in_feat, WThi, WTlo, bias, w5, dinv, y_a, zy);

    lap_kernel<<<NNODE / 4, 256, 0, stream>>>(y_a, y_b, zy, dinv2, row_ptr, col, w5, 1);
    lap_kernel<<<NNODE / 4, 256, 0, stream>>>(y_b, y_a, zy, dinv2, row_ptr, col, w5, 2);
    lap_kernel<<<NNODE / 4, 256, 0, stream>>>(y_a, y_b, zy, dinv2, row_ptr, col, w5, 3);
    lap_last_kernel<<<NNODE / 4, 256, 0, stream>>>(y_b, zy, dinv2, dsqrt, row_ptr, col, w5, Rhi, Rlo);

    gemm2_mfma<<<NTRI, 256, 0, stream>>>(Rhi, Rlo, tab, out);
}

// Round 13
// 511.501 us; speedup vs baseline: 1.3377x; 1.1000x over previous
//
#include <hip/hip_runtime.h>
#include <cstddef>

#define NNODE 10000
#define IND 512
#define HD 256
#define PAD_M 10112    // 79 * 128
#define NTILE 79
#define NTRI (NTILE * (NTILE + 1) / 2)   // 3160 lower-triangle blocks
#define NST ((NTILE + 7) / 8)            // 10 row-supertiles

typedef __attribute__((ext_vector_type(8))) short short8;
typedef __attribute__((ext_vector_type(4))) float floatx4;
typedef __attribute__((ext_vector_type(4))) unsigned short ushortx4;

#define GLOAD_LDS16(gp, lp) __builtin_amdgcn_global_load_lds( \
    (const __attribute__((address_space(1))) unsigned int*)(gp), \
    (__attribute__((address_space(3))) unsigned int*)(lp), 16, 0, 0)

// barrier that waits only on LDS ops (lgkmcnt), NOT on outstanding stores
#define LIGHT_BARRIER() do { \
    asm volatile("s_waitcnt lgkmcnt(0)" ::: "memory"); \
    __builtin_amdgcn_s_barrier(); \
} while (0)

// ---------------------------------------------------------------------------
// 1. count degrees
// ---------------------------------------------------------------------------
__global__ void count_kernel(const int* __restrict__ src, const int* __restrict__ dst,
                             int E, int* __restrict__ cnt_src, int* __restrict__ cnt_dst) {
    int e = blockIdx.x * blockDim.x + threadIdx.x;
    if (e < E) {
        atomicAdd(&cnt_src[src[e]], 1);
        atomicAdd(&cnt_dst[dst[e]], 1);
    }
}

// ---------------------------------------------------------------------------
// 2. dinv, dinv^2, sqrt(deg) + exclusive scan of cnt_dst -> row_ptr
// ---------------------------------------------------------------------------
__global__ __launch_bounds__(1024) void scan_kernel(const int* __restrict__ cnt_src,
                                                    const int* __restrict__ cnt_dst,
                                                    float* __restrict__ dinv,
                                                    float* __restrict__ dinv2,
                                                    float* __restrict__ dsqrt,
                                                    int* __restrict__ row_ptr) {
    int t = threadIdx.x;
    for (int i = t; i < NNODE; i += 1024) {
        float d = fmaxf((float)cnt_src[i], 1.0f);
        float di = rsqrtf(d);
        dinv[i] = di;
        dinv2[i] = di * di;
        dsqrt[i] = sqrtf(d);
    }

    __shared__ int sums[1024];
    const int CH = (NNODE + 1023) / 1024;  // 10
    int base = t * CH;
    int s = 0;
    for (int i = 0; i < CH; ++i) {
        int idx = base + i;
        if (idx < NNODE) s += cnt_dst[idx];
    }
    sums[t] = s;
    __syncthreads();
    for (int off = 1; off < 1024; off <<= 1) {
        int v = (t >= off) ? sums[t - off] : 0;
        __syncthreads();
        sums[t] += v;
        __syncthreads();
    }
    int run = (t == 0) ? 0 : sums[t - 1];
    for (int i = 0; i < CH; ++i) {
        int idx = base + i;
        if (idx < NNODE) { row_ptr[idx] = run; run += cnt_dst[idx]; }
    }
    if (t == 1023) row_ptr[NNODE] = sums[1023];
}

// ---------------------------------------------------------------------------
// 3. fill CSR (by dst)
// ---------------------------------------------------------------------------
__global__ void fill_kernel(const int* __restrict__ src, const int* __restrict__ dst,
                            int E, const int* __restrict__ row_ptr,
                            int* __restrict__ cursor, int* __restrict__ col) {
    int e = blockIdx.x * blockDim.x + threadIdx.x;
    if (e < E) {
        int v = dst[e];
        int pos = row_ptr[v] + atomicAdd(&cursor[v], 1);
        col[pos] = src[e];
    }
}

// ---------------------------------------------------------------------------
// 3b. supertile-ordered (bi,bj) table for gemm2 (8x8-block supertiles)
// ---------------------------------------------------------------------------
__global__ void order_kernel(int* __restrict__ tab) {
    int s = threadIdx.x;                 // supertile id, 0..54
    if (s >= NST * (NST + 1) / 2) return;
    int I = 0;
    while ((I + 1) * (I + 2) / 2 <= s) ++I;
    int J = s - I * (I + 1) / 2;
    auto cnt = [](int Ii, int Jj) {
        int r0 = Ii * 8, r1 = min(r0 + 8, NTILE);
        int c = 0;
        for (int bi = r0; bi < r1; ++bi) {
            int c0 = Jj * 8, c1 = min(min(c0 + 8, NTILE), bi + 1);
            c += max(0, c1 - c0);
        }
        return c;
    };
    int off = 0;
    for (int sp = 0; sp < s; ++sp) {
        int Ip = 0;
        while ((Ip + 1) * (Ip + 2) / 2 <= sp) ++Ip;
        int Jp = sp - Ip * (Ip + 1) / 2;
        off += cnt(Ip, Jp);
    }
    int r0 = I * 8, r1 = min(r0 + 8, NTILE);
    for (int bi = r0; bi < r1; ++bi) {
        int c0 = J * 8, c1 = min(min(c0 + 8, NTILE), bi + 1);
        for (int bj = c0; bj < c1; ++bj)
            tab[off++] = (bi << 16) | bj;
    }
}

// ---------------------------------------------------------------------------
// 4. combine weights w_k
// ---------------------------------------------------------------------------
__global__ void w_kernel(const float* __restrict__ lam, float* __restrict__ w) {
    if (threadIdx.x == 0 && blockIdx.x == 0) {
        float c[5];
        float s0 = 1.0f / (1.0f + expf(-lam[0]));
        c[0] = s0;
        c[1] = s0;  // reference reuses lam[0] for all_h[1]
        c[2] = 1.0f / (1.0f + expf(-lam[1]));
        c[3] = 1.0f / (1.0f + expf(-lam[2]));
        c[4] = 1.0f / (1.0f + expf(-lam[3]));
        const float TH[5][5] = {
            {5.0f, -10.0f,  7.5f, -2.5f, 0.3125f},
            {0.0f,  10.0f, -15.0f, 7.5f, -1.25f },
            {0.0f,   0.0f,  7.5f, -7.5f, 1.875f },
            {0.0f,   0.0f,  0.0f,  2.5f, -1.25f },
            {0.0f,   0.0f,  0.0f,  0.0f, 0.3125f}};
        for (int k = 0; k < 5; ++k) {
            float acc = 0.0f;
            for (int i = 0; i < 5; ++i) acc += c[i] * TH[i][k];
            w[k] = acc;
        }
    }
}

// ---------------------------------------------------------------------------
// 4c. split + transpose W -> WT [HD][IND] bf16 hi/lo
// ---------------------------------------------------------------------------
__global__ void split_wt_kernel(const float* __restrict__ W,
                                unsigned short* __restrict__ WThi,
                                unsigned short* __restrict__ WTlo) {
    int tid = blockIdx.x * blockDim.x + threadIdx.x;  // 0 .. IND*HD-1
    if (tid >= IND * HD) return;
    int n = tid & (HD - 1);
    int k = tid >> 8;
    float r = W[(size_t)k * HD + n];
    unsigned u = __float_as_uint(r);
    float hif = __uint_as_float(u & 0xFFFF0000u);
    float lof = r - hif;
    WThi[(size_t)n * IND + k] = (unsigned short)(u >> 16);
    WTlo[(size_t)n * IND + k] = (unsigned short)(__float_as_uint(lof) >> 16);
}

// ---------------------------------------------------------------------------
// 5. GEMM1 (MFMA, fused in-register hi/lo split of f32 A):
//    h = leaky_relu(in_feat @ W + b); y0 = dinv*h; zy = w0*y0.
// ---------------------------------------------------------------------------
__global__ __launch_bounds__(256) void gemm1_mfma(
    const float* __restrict__ A,
    const unsigned short* __restrict__ WThi, const unsigned short* __restrict__ WTlo,
    const float* __restrict__ bias, const float* __restrict__ w5,
    const float* __restrict__ dinv,
    float* __restrict__ y_out, float* __restrict__ zy) {
    __shared__ __align__(16) char smem[65536];
    float (*Afs)[64] = (float (*)[64])smem;                             // [128][64] f32
    unsigned short (*Bh)[64] = (unsigned short (*)[64])(smem + 32768);  // [128][64] bf16
    unsigned short (*Bl)[64] = (unsigned short (*)[64])(smem + 49152);

    const int brow = blockIdx.x * 128, bcol = blockIdx.y * 128;
    const int t = threadIdx.x;
    const int lane = t & 63;
    const int wave = t >> 6;
    const int wm = wave >> 1, wn = wave & 1;
    const int fr = lane & 15;
    const int kq = lane >> 4;

    floatx4 acc[4][4];
#pragma unroll
    for (int i = 0; i < 4; ++i)
#pragma unroll
        for (int j = 0; j < 4; ++j)
            acc[i][j] = (floatx4){0.f, 0.f, 0.f, 0.f};

    const int arow_l = t >> 4;   // 0..15 per pass
    const int aslot  = t & 15;   // 16B slot within 64-f32 row
    const int brow_l = t >> 3;   // 0..31 per pass
    const int bslot  = t & 7;    // 16B slot within 64-bf16 row

    for (int ks = 0; ks < 8; ++ks) {
        const int k0 = ks * 64;
#pragma unroll
        for (int p = 0; p < 8; ++p) {
            int row = p * 16 + arow_l;
            int grow = brow + row;
            int rowc = grow < NNODE ? grow : 0;   // clamp; garbage rows discarded
            int slot = aslot ^ (row & 15);
            const float* ga = A + (size_t)rowc * IND + k0 + slot * 4;
            GLOAD_LDS16(ga, smem + p * 4096 + t * 16);
        }
#pragma unroll
        for (int p = 0; p < 4; ++p) {
            int row = p * 32 + brow_l;            // output-col within tile, < 128
            int slot = bslot ^ (row & 7);
            const unsigned short* gh = WThi + (size_t)(bcol + row) * IND + k0 + slot * 8;
            const unsigned short* gl = WTlo + (size_t)(bcol + row) * IND + k0 + slot * 8;
            GLOAD_LDS16(gh, smem + 32768 + p * 4096 + t * 16);
            GLOAD_LDS16(gl, smem + 49152 + p * 4096 + t * 16);
        }
        __syncthreads();
#pragma unroll
        for (int kk = 0; kk < 2; ++kk) {
            short8 ahi[4], alo[4], bhi[4], blo[4];
#pragma unroll
            for (int i = 0; i < 4; ++i) {
                int r = wm * 64 + i * 16 + fr;
                int s0 = kk * 8 + kq * 2;
                int X = r & 15;
                floatx4 a0 = *(const floatx4*)&Afs[r][(s0 ^ X) * 4];
                floatx4 a1 = *(const floatx4*)&Afs[r][((s0 + 1) ^ X) * 4];
#pragma unroll
                for (int c = 0; c < 4; ++c) {
                    unsigned u0 = __float_as_uint(a0[c]);
                    float h0 = __uint_as_float(u0 & 0xFFFF0000u);
                    ahi[i][c] = (short)(u0 >> 16);
                    alo[i][c] = (short)(__float_as_uint(a0[c] - h0) >> 16);
                    unsigned u1 = __float_as_uint(a1[c]);
                    float h1 = __uint_as_float(u1 & 0xFFFF0000u);
                    ahi[i][c + 4] = (short)(u1 >> 16);
                    alo[i][c + 4] = (short)(__float_as_uint(a1[c] - h1) >> 16);
                }
            }
#pragma unroll
            for (int j = 0; j < 4; ++j) {
                int r = wn * 64 + j * 16 + fr;
                int sb = (kk * 4 + kq) ^ (r & 7);
                bhi[j] = *(const short8*)&Bh[r][sb * 8];
                blo[j] = *(const short8*)&Bl[r][sb * 8];
            }
#pragma unroll
            for (int i = 0; i < 4; ++i)
#pragma unroll
                for (int j = 0; j < 4; ++j) {
                    acc[i][j] = __builtin_amdgcn_mfma_f32_16x16x32_bf16(ahi[i], bhi[j], acc[i][j], 0, 0, 0);
                    acc[i][j] = __builtin_amdgcn_mfma_f32_16x16x32_bf16(ahi[i], blo[j], acc[i][j], 0, 0, 0);
                    acc[i][j] = __builtin_amdgcn_mfma_f32_16x16x32_bf16(alo[i], bhi[j], acc[i][j], 0, 0, 0);
                }
        }
        __syncthreads();
    }

    float w0 = w5[0];
#pragma unroll
    for (int i = 0; i < 4; ++i) {
#pragma unroll
        for (int j = 0; j < 4; ++j) {
            int gcol = bcol + wn * 64 + j * 16 + fr;   // < 256 always
            float bb = bias[gcol];
#pragma unroll
            for (int r = 0; r < 4; ++r) {
                int grow = brow + wm * 64 + i * 16 + kq * 4 + r;
                if (grow < NNODE) {
                    float v = acc[i][j][r] + bb;
                    v = v > 0.0f ? v : 0.01f * v;
                    float y0 = dinv[grow] * v;
                    y_out[(size_t)grow * HD + gcol] = y0;
                    zy[(size_t)grow * HD + gcol] = w0 * y0;
                }
            }
        }
    }
}

// ---------------------------------------------------------------------------
// 6. y-space Laplacian, full 256 channels, float4/lane (R8/R10 structure):
//    ynew[v] = y[v] - dinv2[v] * sum_{u in N(v)} y[u];  zy += w_k * ynew
// ---------------------------------------------------------------------------
__global__ __launch_bounds__(256) void lap_kernel(
    const float* __restrict__ yin, float* __restrict__ yout,
    float* __restrict__ zy, const float* __restrict__ dinv2,
    const int* __restrict__ row_ptr, const int* __restrict__ col,
    const float* __restrict__ w5, int k) {
    const int g = threadIdx.x >> 6;
    const int lane = threadIdx.x & 63;
    const int v = blockIdx.x * 4 + g;
    if (v >= NNODE) return;
    const float wk = w5[k];
    const int beg = row_ptr[v], end = row_ptr[v + 1];
    float s0 = 0.f, s1 = 0.f, s2 = 0.f, s3 = 0.f;
    const size_t coff = (size_t)lane * 4;
    for (int j = beg; j < end; ++j) {
        int u = col[j];
        floatx4 fv = *(const floatx4*)(yin + (size_t)u * HD + coff);
        s0 += fv[0];
        s1 += fv[1];
        s2 += fv[2];
        s3 += fv[3];
    }
    const float d2 = dinv2[v];
    const size_t idx = (size_t)v * HD + coff;
    floatx4 fi = *(const floatx4*)(yin + idx);
    floatx4 o = {fi[0] - d2 * s0, fi[1] - d2 * s1, fi[2] - d2 * s2, fi[3] - d2 * s3};
    *(floatx4*)(yout + idx) = o;
    floatx4 rc = *(const floatx4*)(zy + idx);
    rc[0] = fmaf(wk, o[0], rc[0]);
    rc[1] = fmaf(wk, o[1], rc[1]);
    rc[2] = fmaf(wk, o[2], rc[2]);
    rc[3] = fmaf(wk, o[3], rc[3]);
    *(floatx4*)(zy + idx) = rc;
}

// ---------------------------------------------------------------------------
// 6b. last y-space Laplacian: recons = (zy + w4*ynew)*sqrt(deg), bf16 hi/lo
// ---------------------------------------------------------------------------
__global__ __launch_bounds__(256) void lap_last_kernel(
    const float* __restrict__ yin, const float* __restrict__ zy,
    const float* __restrict__ dinv2, const float* __restrict__ dsqrt,
    const int* __restrict__ row_ptr, const int* __restrict__ col,
    const float* __restrict__ w5,
    unsigned short* __restrict__ Rhi, unsigned short* __restrict__ Rlo) {
    const int g = threadIdx.x >> 6;
    const int lane = threadIdx.x & 63;
    const int v = blockIdx.x * 4 + g;
    if (v >= NNODE) return;
    const float w4 = w5[4];
    const int beg = row_ptr[v], end = row_ptr[v + 1];
    float s0 = 0.f, s1 = 0.f, s2 = 0.f, s3 = 0.f;
    const size_t coff = (size_t)lane * 4;
    for (int j = beg; j < end; ++j) {
        int u = col[j];
        floatx4 fv = *(const floatx4*)(yin + (size_t)u * HD + coff);
        s0 += fv[0];
        s1 += fv[1];
        s2 += fv[2];
        s3 += fv[3];
    }
    const float d2 = dinv2[v];
    const float ds = dsqrt[v];
    const size_t idx = (size_t)v * HD + coff;
    floatx4 fi = *(const floatx4*)(yin + idx);
    floatx4 rc = *(const floatx4*)(zy + idx);
    float ss[4] = {s0, s1, s2, s3};
    ushortx4 hi, lo;
#pragma unroll
    for (int c = 0; c < 4; ++c) {
        float ynew = fi[c] - d2 * ss[c];
        float r = (rc[c] + w4 * ynew) * ds;
        unsigned u = __float_as_uint(r);
        float hif = __uint_as_float(u & 0xFFFF0000u);
        float lof = r - hif;   // exact (same binade)
        hi[c] = (unsigned short)(u >> 16);
        lo[c] = (unsigned short)(__float_as_uint(lof) >> 16);
    }
    *(ushortx4*)(Rhi + idx) = hi;
    *(ushortx4*)(Rlo + idx) = lo;
}

// ---------------------------------------------------------------------------
// 7. GEMM2 (MFMA): out = sigmoid(R R^T), 128x128 lower-triangle blocks,
//    supertile order (tab). NEW: BK=32 double-buffered 2-phase K-loop
//    (stage next tile BEFORE computing current; one barrier/step so load
//    latency hides under MFMA+ds_read) + slot-XOR LDS swizzle (source-side
//    pre-swizzle + matching read XOR; linear LDS dest as global_load_lds
//    requires). Epilogue: LDS-staged full-line NT writes, light barriers.
// ---------------------------------------------------------------------------
__global__ __launch_bounds__(256) void gemm2_mfma(
    const unsigned short* __restrict__ Rhi,
    const unsigned short* __restrict__ Rlo,
    const int* __restrict__ tab,
    float* __restrict__ out) {
    __shared__ __align__(16) char smem[32768];
    // phase ph buffer: A at shorts [ph*8192, +4096), B at [ph*8192+4096, +4096)

    const int orig = blockIdx.x;
    const int kb = (orig & 7) * (NTRI / 8) + (orig >> 3);
    const int e = tab[kb];
    const int bi = e >> 16, bj = e & 0xffff;
    const int brow = bi * 128, bcol = bj * 128;

    const int t = threadIdx.x;
    const int lane = t & 63;
    const int wave = t >> 6;
    const int wm = wave >> 1, wn = wave & 1;
    const int fr = lane & 15;
    const int kq = lane >> 4;

    floatx4 acc[4][4];
#pragma unroll
    for (int i = 0; i < 4; ++i)
#pragma unroll
        for (int j = 0; j < 4; ++j)
            acc[i][j] = (floatx4){0.f, 0.f, 0.f, 0.f};

    const int srow = t >> 2;        // 0..63 (row within 64-row half)
    const int sslot = t & 3;        // 16B slot within 64B (BK=32 bf16) row

    unsigned short* smem_s = (unsigned short*)smem;

    // stage K-step ks into phase ph (linear LDS dest, XOR-swizzled source)
    auto STAGE = [&](int ph, int ks) {
        const int seg = ks >> 3;
        const int k0 = (ks & 7) * 32;
        const unsigned short* Aseg = (seg < 2) ? Rhi : Rlo;
        const unsigned short* Bseg = (seg == 1) ? Rlo : Rhi;
        unsigned short* base = smem_s + ph * 8192;
#pragma unroll
        for (int p = 0; p < 2; ++p) {
            int row = p * 64 + srow;
            int slot = sslot ^ (row & 3);
            const unsigned short* ga = Aseg + (size_t)(brow + row) * HD + k0 + slot * 8;
            const unsigned short* gb = Bseg + (size_t)(bcol + row) * HD + k0 + slot * 8;
            GLOAD_LDS16(ga, base + p * 2048 + t * 8);
            GLOAD_LDS16(gb, base + 4096 + p * 2048 + t * 8);
        }
    };

    STAGE(0, 0);
    __syncthreads();
    int ph = 0;
    for (int ks = 0; ks < 24; ++ks) {
        if (ks + 1 < 24) STAGE(ph ^ 1, ks + 1);
        const unsigned short* base = smem_s + ph * 8192;
        short8 a[4], b[4];
#pragma unroll
        for (int i = 0; i < 4; ++i) {
            int r = wm * 64 + i * 16 + fr;
            a[i] = *(const short8*)&base[r * 32 + (kq ^ (r & 3)) * 8];
        }
#pragma unroll
        for (int j = 0; j < 4; ++j) {
            int r = wn * 64 + j * 16 + fr;
            b[j] = *(const short8*)&base[4096 + r * 32 + (kq ^ (r & 3)) * 8];
        }
#pragma unroll
        for (int i = 0; i < 4; ++i)
#pragma unroll
            for (int j = 0; j < 4; ++j)
                acc[i][j] = __builtin_amdgcn_mfma_f32_16x16x32_bf16(
                    a[i], b[j], acc[i][j], 0, 0, 0);
        __syncthreads();   // drains this step's stage (next buf) + our ds_reads
        ph ^= 1;
    }

    const int tr = t >> 3, tl = t & 7;

    // --- direct tile: stage 32-row chunks in LDS, full-line NT writes ---
    {
        float (*sd)[132] = (float (*)[132])smem;
        const int cmaxd = NNODE - bcol;
#pragma unroll
        for (int c0 = 0; c0 < 128; c0 += 32) {
            if (wm == (c0 >> 6)) {
                int ibase = (c0 & 63) >> 4;
#pragma unroll
                for (int ii = 0; ii < 2; ++ii) {
                    int i = ibase + ii;
#pragma unroll
                    for (int j = 0; j < 4; ++j)
#pragma unroll
                        for (int r = 0; r < 4; ++r) {
                            float s = 1.0f / (1.0f + __expf(-acc[i][j][r]));
                            sd[ii * 16 + kq * 4 + r][wn * 64 + j * 16 + fr] = s;
                        }
                }
            }
            LIGHT_BARRIER();
            int grow = brow + c0 + tr;
            if (grow < NNODE) {
                float* orow = out + (size_t)grow * NNODE + bcol;
#pragma unroll
                for (int k = 0; k < 4; ++k) {
                    int x = tl * 4 + k * 32;
                    if (x + 4 <= cmaxd) {
                        floatx4 v = {sd[tr][x], sd[tr][x + 1], sd[tr][x + 2], sd[tr][x + 3]};
                        __builtin_nontemporal_store(v, (floatx4*)(orow + x));
                    } else {
                        for (int xx = x; xx < cmaxd && xx < x + 4; ++xx)
                            __builtin_nontemporal_store(sd[tr][xx], orow + xx);
                    }
                }
            }
            LIGHT_BARRIER();
        }
    }

    // --- mirror tile via LDS transpose (skip diagonal) ---
    if (bi == bj) return;
    {
        float (*trs)[129] = (float (*)[129])smem;
        const int cmax = NNODE - brow;
#pragma unroll
        for (int c0 = 0; c0 < 128; c0 += 32) {
            if (wn == (c0 >> 6)) {
                int jlo = (c0 & 63) >> 4;
#pragma unroll
                for (int jj = 0; jj < 2; ++jj) {
                    int j = jlo + jj;
#pragma unroll
                    for (int i = 0; i < 4; ++i)
#pragma unroll
                        for (int r = 0; r < 4; ++r) {
                            float s = 1.0f / (1.0f + __expf(-acc[i][j][r]));
                            trs[jj * 16 + fr][wm * 64 + i * 16 + kq * 4 + r] = s;
                        }
                }
            }
            LIGHT_BARRIER();
            int gr = bcol + c0 + tr;   // < NNODE (bj < bi)
            float* orow = out + (size_t)gr * NNODE + brow;
#pragma unroll
            for (int k = 0; k < 4; ++k) {
                int x = tl * 4 + k * 32;
                if (x + 4 <= cmax) {
                    floatx4 v = {trs[tr][x], trs[tr][x + 1], trs[tr][x + 2], trs[tr][x + 3]};
                    __builtin_nontemporal_store(v, (floatx4*)(orow + x));
                } else {
                    for (int xx = x; xx < cmax && xx < x + 4; ++xx)
                        __builtin_nontemporal_store(trs[tr][xx], orow + xx);
                }
            }
            LIGHT_BARRIER();
        }
    }
}

// ---------------------------------------------------------------------------
extern "C" void kernel_launch(void* const* d_in, const int* in_sizes, int n_in,
                              void* d_out, int out_size, void* d_ws, size_t ws_size,
                              hipStream_t stream) {
    const float* in_feat = (const float*)d_in[0];
    const float* W       = (const float*)d_in[1];
    const float* bias    = (const float*)d_in[2];
    const float* lam     = (const float*)d_in[3];
    const int*   src     = (const int*)d_in[4];
    const int*   dst     = (const int*)d_in[5];
    const int    E       = in_sizes[4];
    float* out = (float*)d_out;

    char* p = (char*)d_ws;
    auto alloc = [&](size_t bytes) -> void* {
        void* r = (void*)p;
        p += (bytes + 255) & ~(size_t)255;
        return r;
    };
    int*   cnts    = (int*)alloc(3 * NNODE * sizeof(int));
    int*   cnt_src = cnts;
    int*   cnt_dst = cnts + NNODE;
    int*   cursor  = cnts + 2 * NNODE;
    int*   row_ptr = (int*)alloc((NNODE + 1) * sizeof(int));
    int*   col     = (int*)alloc((size_t)E * sizeof(int));
    float* dinv    = (float*)alloc(NNODE * sizeof(float));
    float* dinv2   = (float*)alloc(NNODE * sizeof(float));
    float* dsqrt   = (float*)alloc(NNODE * sizeof(float));
    float* w5      = (float*)alloc(8 * sizeof(float));
    int*   tab     = (int*)alloc(NTRI * sizeof(int));
    float* y_a     = (float*)alloc((size_t)NNODE * HD * sizeof(float));
    float* y_b     = (float*)alloc((size_t)NNODE * HD * sizeof(float));
    float* zy      = (float*)alloc((size_t)NNODE * HD * sizeof(float));
    unsigned short* Rhi  = (unsigned short*)alloc((size_t)PAD_M * HD * sizeof(unsigned short));
    unsigned short* Rlo  = (unsigned short*)alloc((size_t)PAD_M * HD * sizeof(unsigned short));
    unsigned short* WThi = (unsigned short*)alloc((size_t)HD * IND * sizeof(unsigned short));
    unsigned short* WTlo = (unsigned short*)alloc((size_t)HD * IND * sizeof(unsigned short));

    hipMemsetAsync(cnts, 0, 3 * NNODE * sizeof(int), stream);
    hipMemsetAsync(Rhi + (size_t)NNODE * HD, 0, (size_t)(PAD_M - NNODE) * HD * 2, stream);
    hipMemsetAsync(Rlo + (size_t)NNODE * HD, 0, (size_t)(PAD_M - NNODE) * HD * 2, stream);

    int eb = (E + 255) / 256;
    count_kernel<<<eb, 256, 0, stream>>>(src, dst, E, cnt_src, cnt_dst);
    w_kernel<<<1, 64, 0, stream>>>(lam, w5);
    order_kernel<<<1, 64, 0, stream>>>(tab);
    scan_kernel<<<1, 1024, 0, stream>>>(cnt_src, cnt_dst, dinv, dinv2, dsqrt, row_ptr);
    fill_kernel<<<eb, 256, 0, stream>>>(src, dst, E, row_ptr, cursor, col);

    split_wt_kernel<<<(IND * HD + 255) / 256, 256, 0, stream>>>(W, WThi, WTlo);

    dim3 g1(NTILE, HD / 128);
    gemm1_mfma<<<g1, 256, 0, stream>>>(in_feat, WThi, WTlo, bias, w5, dinv, y_a, zy);

    lap_kernel<<<NNODE / 4, 256, 0, stream>>>(y_a, y_b, zy, dinv2, row_ptr, col, w5, 1);
    lap_kernel<<<NNODE / 4, 256, 0, stream>>>(y_b, y_a, zy, dinv2, row_ptr, col, w5, 2);
    lap_kernel<<<NNODE / 4, 256, 0, stream>>>(y_a, y_b, zy, dinv2, row_ptr, col, w5, 3);
    lap_last_kernel<<<NNODE / 4, 256, 0, stream>>>(y_b, zy, dinv2, dsqrt, row_ptr, col, w5, Rhi, Rlo);

    gemm2_mfma<<<NTRI, 256, 0, stream>>>(Rhi, Rlo, tab, out);
}